// Round 15
// baseline (293.117 us; speedup 1.0000x reference)
//
#include <hip/hip_runtime.h>

#define N_PTS   200000
#define N_EDGES 1600000
#define MEM_SIZE (1 << 27)

#define NP   16                               // node parts
#define NPB  12800                            // nodes/part; 102.4KB LDS -> 1 block/CU
#define EP   16                               // edge slices; W = 25.6 MB
#define EPS  (N_EDGES / EP)                   // 100000 edges per slice
#define EPS4 (EPS / 2)                        // 50000 int4 (2 edges) per slice
#define NBLK (NP * EP)                        // 256 blocks = exactly 1 per CU
#define NTHR 1024                             // 16 waves/block
#define NF4  (MEM_SIZE / 4)                   // 33,554,432 float4
#define SHARE (NF4 / NBLK)                    // 131,072 f4 per block (contiguous)
#define SCAN_L 256                            // waves 0-3: dedicated scan lanes
#define CPY_A  768                            // waves 4-15: phase-A copy threads
#define ITER_A 44                             // 768*44 = 33,792 f4 (~26% of share)
#define OFF_B  (CPY_A * ITER_A)               // 33,792
#define ITER_B ((SHARE - OFF_B) / NTHR)       // 95 exact (97,280 f4)

__device__ __forceinline__ void upd2(unsigned* __restrict__ mn1, unsigned* __restrict__ mn2,
                                     int a, unsigned i) {
    if ((unsigned)a < NPB) {
        unsigned old = atomicMin(&mn1[a], i);
        unsigned c = (i < old) ? old : i;      // displaced value or losing insert
        atomicMin(&mn2[a], c);                 // c==0xFFFFFFFF is a value no-op
    }
}

__device__ __forceinline__ void proc(unsigned* __restrict__ mn1, unsigned* __restrict__ mn2,
                                     int lo, int4 p, int g /* global int4 index */) {
    // int4 g holds edges 2g (p.x,p.y) and 2g+1 (p.z,p.w)
    unsigned ia0 = (unsigned)(2 * g);
    unsigned ib0 = (unsigned)(2 * g + N_EDGES);
    upd2(mn1, mn2, p.x - lo, ia0);
    upd2(mn1, mn2, p.y - lo, ib0);
    upd2(mn1, mn2, p.z - lo, ia0 + 1u);
    upd2(mn1, mn2, p.w - lo, ib0 + 1u);
}

// Wave-specialized fusion: waves 0-3 run the whole slice scan (LDS-atomic /
// VALU pipes), waves 4-15 stream copy part A (VMEM pipe) on the same CU.
// SIMD round-robin fills scan-chain stalls with copy issues (m114-style
// co-scheduling). Then all 16 waves write W and finish copy part B.
__global__ __launch_bounds__(NTHR) void fused_copy_scan(const float4* __restrict__ src,
                                                        float4* __restrict__ dst,
                                                        const int4* __restrict__ edges4,
                                                        unsigned long long* __restrict__ W) {
    __shared__ unsigned mn1[NPB];
    __shared__ unsigned mn2[NPB];

    int b  = blockIdx.x;
    int ep = b & 15;                 // slice
    int np = b >> 4;                 // node part 0..15
    int lo = np * NPB;
    int t  = threadIdx.x;

    for (int j = t; j < NPB; j += NTHR) { mn1[j] = 0xFFFFFFFFu; mn2[j] = 0xFFFFFFFFu; }
    __syncthreads();

    if (t < SCAN_L) {
        // ---- scan waves: 256 lanes cover 50,000 int4s, 4-deep load batches
        int q0 = ep * EPS4;
        int k = t;
        for (; k + 3 * SCAN_L < EPS4; k += 4 * SCAN_L) {
            int4 p0 = edges4[q0 + k];
            int4 p1 = edges4[q0 + k + SCAN_L];
            int4 p2 = edges4[q0 + k + 2 * SCAN_L];
            int4 p3 = edges4[q0 + k + 3 * SCAN_L];
            proc(mn1, mn2, lo, p0, q0 + k);
            proc(mn1, mn2, lo, p1, q0 + k + SCAN_L);
            proc(mn1, mn2, lo, p2, q0 + k + 2 * SCAN_L);
            proc(mn1, mn2, lo, p3, q0 + k + 3 * SCAN_L);
        }
        for (; k < EPS4; k += SCAN_L) {
            int4 p = edges4[q0 + k];
            proc(mn1, mn2, lo, p, q0 + k);
        }
    } else {
        // ---- copy waves: part A of this block's contiguous share
        int u  = t - SCAN_L;
        int cb = b * SHARE + u;
        #pragma unroll 4
        for (int i = 0; i < ITER_A; ++i)
            dst[cb + i * CPY_A] = src[cb + i * CPY_A];
    }
    __syncthreads();

    // W write (all waves, coalesced)
    for (int j = t; j < NPB; j += NTHR) {
        int n = lo + j;
        if (n < N_PTS)
            W[(size_t)ep * N_PTS + n] =
                ((unsigned long long)mn2[j] << 32) | (unsigned long long)mn1[j];
    }

    // copy part B (all 16 waves)
    int cb = b * SHARE + OFF_B + t;
    #pragma unroll 4
    for (int i = 0; i < ITER_B; ++i)
        dst[cb + i * NTHR] = src[cb + i * NTHR];
}

__device__ __forceinline__ int quant6(float d) {
    // match jnp: clip(round((d + 1)/2 * 63), 0, 63); jnp.round = half-to-even -> rintf
    float x = ((d + 1.0f) / 2.0f) * 63.0f;
    float r = rintf(x);
    r = fminf(fmaxf(r, 0.0f), 63.0f);
    return (int)r;
}

__global__ void finalize(const float* __restrict__ pts, const float* __restrict__ tex,
                         const int2* __restrict__ edges,
                         const unsigned long long* __restrict__ W,
                         float* __restrict__ out) {
    int n = blockIdx.x * blockDim.x + threadIdx.x;
    if (n >= N_PTS) return;

    // merge EP per-slice (m1,m2) pairs -> global two smallest (all indices distinct)
    unsigned int k1 = 0xFFFFFFFFu, k2 = 0xFFFFFFFFu;
    #pragma unroll
    for (int s = 0; s < EP; ++s) {
        unsigned long long pr = W[(size_t)s * N_PTS + n];
        unsigned int m1 = (unsigned int)(pr & 0xFFFFFFFFu);
        unsigned int m2 = (unsigned int)(pr >> 32);
        if (m1 < k1) { k2 = k1; k1 = m1; } else if (m1 < k2) { k2 = m1; }
        if (m2 < k2 && m2 > k1) { k2 = m2; }
    }

    float px = pts[2 * n], py = pts[2 * n + 1];
    int t = (tex[n] > 0.7f) ? 1 : 0;

    int v0x = 0, v0y = 0, t0 = 0, v1x = 0, v1y = 0, t1 = 0;

    if (k1 < 2u * N_EDGES) {
        int k = (int)k1;
        int2 e = edges[(k < N_EDGES) ? k : (k - N_EDGES)];
        int dst = (k < N_EDGES) ? e.y : e.x;
        v0x = quant6(pts[2 * dst] - px);
        v0y = quant6(pts[2 * dst + 1] - py);
        t0 = (tex[dst] > 0.7f) ? 1 : 0;
    }
    if (k2 < 2u * N_EDGES) {
        int k = (int)k2;
        int2 e = edges[(k < N_EDGES) ? k : (k - N_EDGES)];
        int dst = (k < N_EDGES) ? e.y : e.x;
        v1x = quant6(pts[2 * dst] - px);
        v1y = quant6(pts[2 * dst + 1] - py);
        t1 = (tex[dst] > 0.7f) ? 1 : 0;
    }

    // hash keeps only cols 0..4 (col4 masked to 3 bits); each rel-variant
    // appears 6 times in rel_all (2 builds x 3 identity-rolls / 3 swap-rolls).
    int h_id = t | (v0x << 6) | (v0y << 12) | (t0 << 18) | ((v1x & 7) << 24);
    int h_sw = t | (v1x << 6) | (v1y << 12) | (t1 << 18) | ((v0x & 7) << 24);

    atomicAdd(&out[h_id], 6.0f);
    atomicAdd(&out[h_sw], 6.0f);
}

extern "C" void kernel_launch(void* const* d_in, const int* in_sizes, int n_in,
                              void* d_out, int out_size, void* d_ws, size_t ws_size,
                              hipStream_t stream) {
    const float* pts   = (const float*)d_in[0];
    const float* tex   = (const float*)d_in[1];
    const int2*  edges = (const int2*)d_in[2];   // int64 in ref -> int32 on device
    const float* mem   = (const float*)d_in[3];
    float*       out   = (float*)d_out;

    unsigned long long* W = (unsigned long long*)d_ws;   // 16 * 200K * 8B = 25.6 MB

    fused_copy_scan<<<NBLK, NTHR, 0, stream>>>(
        (const float4*)mem, (float4*)out, (const int4*)edges, W);
    finalize<<<(N_PTS + 255) / 256, 256, 0, stream>>>(pts, tex, edges, W, out);
}

// Round 17
// 241.789 us; speedup vs baseline: 1.2123x; 1.2123x over previous
//
#include <hip/hip_runtime.h>

#define N_PTS   200000
#define N_EDGES 1600000
#define MEM_SIZE (1 << 27)

#define NP   16                               // node parts
#define NPB  12800                            // nodes/part; 102.4KB LDS -> 1 block/CU
#define EP   16                               // edge slices; W = 25.6 MB
#define EPS  (N_EDGES / EP)                   // 100000 edges per slice
#define EPS4 (EPS / 2)                        // 50000 int4 (2 edges) per slice
#define NBLK (NP * EP)                        // 256 blocks = exactly 1 per CU
#define NTHR 1024                             // 16 waves/block (LDS-capped occupancy)
#define NF4  (MEM_SIZE / 4)                   // 33,554,432 float4
#define CSTRIDE (NBLK * NTHR)                 // 262,144 threads -> 128 f4/thread exact
#define CITER (NF4 / CSTRIDE)                 // 128
#define SITER ((EPS4 + NTHR - 1) / NTHR)      // 49

typedef float f32x4 __attribute__((ext_vector_type(4)));   // native vec: nontemporal-ok

__device__ __forceinline__ void upd2(unsigned* __restrict__ mn1, unsigned* __restrict__ mn2,
                                     int a, unsigned i) {
    if ((unsigned)a < NPB) {
        unsigned old = atomicMin(&mn1[a], i);
        unsigned c = (i < old) ? old : i;      // displaced value or losing insert
        atomicMin(&mn2[a], c);                 // c==0xFFFFFFFF is a value no-op
    }
}

__device__ __forceinline__ void proc(unsigned* __restrict__ mn1, unsigned* __restrict__ mn2,
                                     int lo, int4 p, int g /* global int4 index */) {
    // int4 g holds edges 2g (p.x,p.y) and 2g+1 (p.z,p.w)
    unsigned ia0 = (unsigned)(2 * g);
    unsigned ib0 = (unsigned)(2 * g + N_EDGES);
    upd2(mn1, mn2, p.x - lo, ia0);
    upd2(mn1, mn2, p.y - lo, ib0);
    upd2(mn1, mn2, p.z - lo, ia0 + 1u);
    upd2(mn1, mn2, p.w - lo, ib0 + 1u);
}

// Fused copy + LDS 2-min scan (r14 structure, best=237us) with two memory
// fixes: (1) NON-TEMPORAL copy loads/stores — the 1.07GB touch-once stream
// no longer evicts the per-XCD edge slices (1.6MB vs 4MB L2), so the NP-fold
// slice re-reads become L2 hits; (2) edge load issued BEFORE the copy load
// in each iteration, so the in-order vmcnt wait for the copy store already
// covers the (faster) edge load — no injected stalls.
__global__ __launch_bounds__(NTHR) void fused_copy_scan(const f32x4* __restrict__ src,
                                                        f32x4* __restrict__ dst,
                                                        const int4* __restrict__ edges4,
                                                        unsigned long long* __restrict__ W) {
    __shared__ unsigned mn1[NPB];
    __shared__ unsigned mn2[NPB];

    int b  = blockIdx.x;
    int ep = b & 15;                 // slice
    int np = b >> 4;                 // node part 0..15
    int lo = np * NPB;
    int t  = threadIdx.x;

    for (int j = t; j < NPB; j += NTHR) { mn1[j] = 0xFFFFFFFFu; mn2[j] = 0xFFFFFFFFu; }
    __syncthreads();

    int q0 = ep * EPS4;              // slice start, int4 units
    int cbase = b * NTHR + t;        // copy index, stride CSTRIDE

    #pragma unroll 8
    for (int j = 0; j < CITER; ++j) {
        int ci = cbase + j * CSTRIDE;
        int k = t + j * NTHR;
        bool have = (j < SITER) && (k < EPS4);
        int4 p;
        if (have) p = edges4[q0 + k];                      // edge load first (L2-resident)
        f32x4 v = __builtin_nontemporal_load(&src[ci]);    // streaming read
        __builtin_nontemporal_store(v, &dst[ci]);          // streaming write
        if (have) proc(mn1, mn2, lo, p, q0 + k);
    }
    __syncthreads();

    for (int j = t; j < NPB; j += NTHR) {
        int n = lo + j;
        if (n < N_PTS)
            W[(size_t)ep * N_PTS + n] =
                ((unsigned long long)mn2[j] << 32) | (unsigned long long)mn1[j];
    }
}

__device__ __forceinline__ int quant6(float d) {
    // match jnp: clip(round((d + 1)/2 * 63), 0, 63); jnp.round = half-to-even -> rintf
    float x = ((d + 1.0f) / 2.0f) * 63.0f;
    float r = rintf(x);
    r = fminf(fmaxf(r, 0.0f), 63.0f);
    return (int)r;
}

__global__ void finalize(const float* __restrict__ pts, const float* __restrict__ tex,
                         const int2* __restrict__ edges,
                         const unsigned long long* __restrict__ W,
                         float* __restrict__ out) {
    int n = blockIdx.x * blockDim.x + threadIdx.x;
    if (n >= N_PTS) return;

    // merge EP per-slice (m1,m2) pairs -> global two smallest (all indices distinct)
    unsigned int k1 = 0xFFFFFFFFu, k2 = 0xFFFFFFFFu;
    #pragma unroll
    for (int s = 0; s < EP; ++s) {
        unsigned long long pr = W[(size_t)s * N_PTS + n];
        unsigned int m1 = (unsigned int)(pr & 0xFFFFFFFFu);
        unsigned int m2 = (unsigned int)(pr >> 32);
        if (m1 < k1) { k2 = k1; k1 = m1; } else if (m1 < k2) { k2 = m1; }
        if (m2 < k2 && m2 > k1) { k2 = m2; }
    }

    float px = pts[2 * n], py = pts[2 * n + 1];
    int t = (tex[n] > 0.7f) ? 1 : 0;

    int v0x = 0, v0y = 0, t0 = 0, v1x = 0, v1y = 0, t1 = 0;

    if (k1 < 2u * N_EDGES) {
        int k = (int)k1;
        int2 e = edges[(k < N_EDGES) ? k : (k - N_EDGES)];
        int dst = (k < N_EDGES) ? e.y : e.x;
        v0x = quant6(pts[2 * dst] - px);
        v0y = quant6(pts[2 * dst + 1] - py);
        t0 = (tex[dst] > 0.7f) ? 1 : 0;
    }
    if (k2 < 2u * N_EDGES) {
        int k = (int)k2;
        int2 e = edges[(k < N_EDGES) ? k : (k - N_EDGES)];
        int dst = (k < N_EDGES) ? e.y : e.x;
        v1x = quant6(pts[2 * dst] - px);
        v1y = quant6(pts[2 * dst + 1] - py);
        t1 = (tex[dst] > 0.7f) ? 1 : 0;
    }

    // hash keeps only cols 0..4 (col4 masked to 3 bits); each rel-variant
    // appears 6 times in rel_all (2 builds x 3 identity-rolls / 3 swap-rolls).
    int h_id = t | (v0x << 6) | (v0y << 12) | (t0 << 18) | ((v1x & 7) << 24);
    int h_sw = t | (v1x << 6) | (v1y << 12) | (t1 << 18) | ((v0x & 7) << 24);

    atomicAdd(&out[h_id], 6.0f);
    atomicAdd(&out[h_sw], 6.0f);
}

extern "C" void kernel_launch(void* const* d_in, const int* in_sizes, int n_in,
                              void* d_out, int out_size, void* d_ws, size_t ws_size,
                              hipStream_t stream) {
    const float* pts   = (const float*)d_in[0];
    const float* tex   = (const float*)d_in[1];
    const int2*  edges = (const int2*)d_in[2];   // int64 in ref -> int32 on device
    const float* mem   = (const float*)d_in[3];
    float*       out   = (float*)d_out;

    unsigned long long* W = (unsigned long long*)d_ws;   // 16 * 200K * 8B = 25.6 MB

    fused_copy_scan<<<NBLK, NTHR, 0, stream>>>(
        (const f32x4*)mem, (f32x4*)out, (const int4*)edges, W);
    finalize<<<(N_PTS + 255) / 256, 256, 0, stream>>>(pts, tex, edges, W, out);
}

// Round 19
// 239.519 us; speedup vs baseline: 1.2238x; 1.0095x over previous
//
#include <hip/hip_runtime.h>

#define N_PTS   200000
#define N_EDGES 1600000
#define MEM_SIZE (1 << 27)

#define NP   16                               // node parts
#define NPB  12800                            // nodes/part; 102.4KB LDS -> 1 block/CU
#define EP   16                               // edge slices; W = 25.6 MB
#define EPS  (N_EDGES / EP)                   // 100000 edges per slice
#define EPS4 (EPS / 2)                        // 50000 int4 (2 edges) per slice
#define NBLK (NP * EP)                        // 256 blocks = exactly 1 per CU
#define NTHR 1024                             // 16 waves/block
#define NF4  (MEM_SIZE / 4)                   // 33,554,432 float4
#define CSTRIDE (NBLK * NTHR)                 // 262,144 threads
#define CITER 128                             // total f4 iters per thread
// Max possible hash = 1 + 63<<6 + 63<<12 + 1<<18 + 7<<24 = 117,964,737 (float idx).
// CIT1 = 113 -> K1 copies floats [0, 118,489,088) ⊇ all hash targets; K2's tail
// copy (floats >= 118,489,088) is disjoint from every finalize atomicAdd. No race.
#define CIT1  113
#define CIT2  (CITER - CIT1)                  // 15 iters in K2 (62.9 MB tail)
#define OFF2  (CIT1 * CSTRIDE)
#define SITER ((EPS4 + NTHR - 1) / NTHR)      // 49

__device__ __forceinline__ void upd2(unsigned* __restrict__ mn1, unsigned* __restrict__ mn2,
                                     int a, unsigned i) {
    if ((unsigned)a < NPB) {
        unsigned old = atomicMin(&mn1[a], i);
        unsigned c = (i < old) ? old : i;      // displaced value or losing insert
        atomicMin(&mn2[a], c);                 // c==0xFFFFFFFF is a value no-op
    }
}

__device__ __forceinline__ void proc(unsigned* __restrict__ mn1, unsigned* __restrict__ mn2,
                                     int lo, int4 p, int g /* global int4 index */) {
    // int4 g holds edges 2g (p.x,p.y) and 2g+1 (p.z,p.w)
    unsigned ia0 = (unsigned)(2 * g);
    unsigned ib0 = (unsigned)(2 * g + N_EDGES);
    upd2(mn1, mn2, p.x - lo, ia0);
    upd2(mn1, mn2, p.y - lo, ib0);
    upd2(mn1, mn2, p.z - lo, ia0 + 1u);
    upd2(mn1, mn2, p.w - lo, ib0 + 1u);
}

// K1: r14's proven fused copy+scan, copy truncated at CIT1=113.
__global__ __launch_bounds__(NTHR) void fused_copy_scan(const float4* __restrict__ src,
                                                        float4* __restrict__ dst,
                                                        const int4* __restrict__ edges4,
                                                        unsigned long long* __restrict__ W) {
    __shared__ unsigned mn1[NPB];
    __shared__ unsigned mn2[NPB];

    int b  = blockIdx.x;
    int ep = b & 15;                 // slice
    int np = b >> 4;                 // node part 0..15
    int lo = np * NPB;
    int t  = threadIdx.x;

    for (int j = t; j < NPB; j += NTHR) { mn1[j] = 0xFFFFFFFFu; mn2[j] = 0xFFFFFFFFu; }
    __syncthreads();

    int q0 = ep * EPS4;              // slice start, int4 units
    int cbase = b * NTHR + t;        // copy index, stride CSTRIDE

    #pragma unroll 8
    for (int j = 0; j < CIT1; ++j) {
        int ci = cbase + j * CSTRIDE;
        float4 v = src[ci];
        int k = t + j * NTHR;
        bool have = (j < SITER) && (k < EPS4);
        int4 p;
        if (have) p = edges4[q0 + k];
        dst[ci] = v;
        if (have) proc(mn1, mn2, lo, p, q0 + k);
    }
    __syncthreads();

    for (int j = t; j < NPB; j += NTHR) {
        int n = lo + j;
        if (n < N_PTS)
            W[(size_t)ep * N_PTS + n] =
                ((unsigned long long)mn2[j] << 32) | (unsigned long long)mn1[j];
    }
}

__device__ __forceinline__ int quant6(float d) {
    // match jnp: clip(round((d + 1)/2 * 63), 0, 63); jnp.round = half-to-even -> rintf
    float x = ((d + 1.0f) / 2.0f) * 63.0f;
    float r = rintf(x);
    r = fminf(fmaxf(r, 0.0f), 63.0f);
    return (int)r;
}

// K2: finalize (W-merge + gathers + hash + 2 atomicAdds, all targets in K1's
// already-copied region) + the disjoint 62.9MB copy tail to hide it under.
__global__ __launch_bounds__(NTHR) void k2_tail(const float4* __restrict__ src,
                                                float4* __restrict__ dst,
                                                const float* __restrict__ pts,
                                                const float* __restrict__ tex,
                                                const int2* __restrict__ edges,
                                                const unsigned long long* __restrict__ W,
                                                float* __restrict__ out) {
    int b = blockIdx.x, t = threadIdx.x;
    int n = b * NTHR + t;

    if (n < N_PTS) {
        // merge EP per-slice (m1,m2) pairs -> global two smallest
        unsigned int k1 = 0xFFFFFFFFu, k2 = 0xFFFFFFFFu;
        #pragma unroll
        for (int s = 0; s < EP; ++s) {
            unsigned long long pr = W[(size_t)s * N_PTS + n];
            unsigned int m1 = (unsigned int)(pr & 0xFFFFFFFFu);
            unsigned int m2 = (unsigned int)(pr >> 32);
            if (m1 < k1) { k2 = k1; k1 = m1; } else if (m1 < k2) { k2 = m1; }
            if (m2 < k2 && m2 > k1) { k2 = m2; }
        }

        float px = pts[2 * n], py = pts[2 * n + 1];
        int tb = (tex[n] > 0.7f) ? 1 : 0;

        int v0x = 0, v0y = 0, t0 = 0, v1x = 0, v1y = 0, t1 = 0;

        if (k1 < 2u * N_EDGES) {
            int k = (int)k1;
            int2 e = edges[(k < N_EDGES) ? k : (k - N_EDGES)];
            int dst_n = (k < N_EDGES) ? e.y : e.x;
            v0x = quant6(pts[2 * dst_n] - px);
            v0y = quant6(pts[2 * dst_n + 1] - py);
            t0 = (tex[dst_n] > 0.7f) ? 1 : 0;
        }
        if (k2 < 2u * N_EDGES) {
            int k = (int)k2;
            int2 e = edges[(k < N_EDGES) ? k : (k - N_EDGES)];
            int dst_n = (k < N_EDGES) ? e.y : e.x;
            v1x = quant6(pts[2 * dst_n] - px);
            v1y = quant6(pts[2 * dst_n + 1] - py);
            t1 = (tex[dst_n] > 0.7f) ? 1 : 0;
        }

        // hash keeps only cols 0..4 (col4 masked to 3 bits); each rel-variant
        // appears 6 times in rel_all (2 builds x 3 id-rolls / 3 swap-rolls).
        int h_id = tb | (v0x << 6) | (v0y << 12) | (t0 << 18) | ((v1x & 7) << 24);
        int h_sw = tb | (v1x << 6) | (v1y << 12) | (t1 << 18) | ((v0x & 7) << 24);

        atomicAdd(&out[h_id], 6.0f);
        atomicAdd(&out[h_sw], 6.0f);
    }

    // copy tail (iterations 113..127; floats >= 118,489,088 — beyond max hash)
    int cbase = OFF2 + b * NTHR + t;
    #pragma unroll 8
    for (int j = 0; j < CIT2; ++j)
        dst[cbase + j * CSTRIDE] = src[cbase + j * CSTRIDE];
}

extern "C" void kernel_launch(void* const* d_in, const int* in_sizes, int n_in,
                              void* d_out, int out_size, void* d_ws, size_t ws_size,
                              hipStream_t stream) {
    const float* pts   = (const float*)d_in[0];
    const float* tex   = (const float*)d_in[1];
    const int2*  edges = (const int2*)d_in[2];   // int64 in ref -> int32 on device
    const float* mem   = (const float*)d_in[3];
    float*       out   = (float*)d_out;

    unsigned long long* W = (unsigned long long*)d_ws;   // 16 * 200K * 8B = 25.6 MB

    fused_copy_scan<<<NBLK, NTHR, 0, stream>>>(
        (const float4*)mem, (float4*)out, (const int4*)edges, W);
    k2_tail<<<NBLK, NTHR, 0, stream>>>(
        (const float4*)mem, (float4*)out, pts, tex, edges, W, out);
}

// Round 20
// 239.183 us; speedup vs baseline: 1.2255x; 1.0014x over previous
//
#include <hip/hip_runtime.h>

#define N_PTS   200000
#define N_EDGES 1600000
#define MEM_SIZE (1 << 27)

#define NP   16                               // node parts
#define NPB  12800                            // nodes/part; 102.4KB LDS -> 1 block/CU
#define EP   16                               // edge slices; W = 25.6 MB
#define EPS  (N_EDGES / EP)                   // 100000 edges per slice
#define NBLK (NP * EP)                        // 256 blocks = exactly 1 per CU
#define NTHR 1024                             // 16 waves/block
#define NF4  (MEM_SIZE / 4)                   // 33,554,432 float4
#define CSTRIDE (NBLK * NTHR)                 // 262,144 threads
#define CITER (NF4 / CSTRIDE)                 // 128 f4 iters per thread
#define SIT2 ((EPS + NTHR - 1) / NTHR)        // 98: one int2 edge per thread per iter

__device__ __forceinline__ void upd2(unsigned* __restrict__ mn1, unsigned* __restrict__ mn2,
                                     int a, unsigned i) {
    if ((unsigned)a < NPB) {
        unsigned old = atomicMin(&mn1[a], i);
        unsigned c = (i < old) ? old : i;      // displaced value or losing insert
        atomicMin(&mn2[a], c);                 // c==0xFFFFFFFF is a value no-op
    }
}

// Fused copy + LDS 2-min scan, SMOOTHED: one edge (2 probes) per thread per
// iteration across 98 of 128 copy iterations, instead of one int4 (4 probes)
// across 49. Halves per-iteration LDS-atomic pressure so the HBM copy stream
// stays fed through the whole kernel (r14's scan was concentrated in the
// first 38% of iterations -> bursty LDS issue, drained copy pipeline).
__global__ __launch_bounds__(NTHR) void fused_copy_scan(const float4* __restrict__ src,
                                                        float4* __restrict__ dst,
                                                        const int2* __restrict__ edges2,
                                                        unsigned long long* __restrict__ W) {
    __shared__ unsigned mn1[NPB];
    __shared__ unsigned mn2[NPB];

    int b  = blockIdx.x;
    int ep = b & 15;                 // slice
    int np = b >> 4;                 // node part 0..15
    int lo = np * NPB;
    int t  = threadIdx.x;

    for (int j = t; j < NPB; j += NTHR) { mn1[j] = 0xFFFFFFFFu; mn2[j] = 0xFFFFFFFFu; }
    __syncthreads();

    int e0 = ep * EPS;               // slice start, edge units
    int cbase = b * NTHR + t;        // copy index, stride CSTRIDE

    #pragma unroll 8
    for (int j = 0; j < CITER; ++j) {
        int ci = cbase + j * CSTRIDE;
        float4 v = src[ci];
        int k = t + j * NTHR;
        bool have = (j < SIT2) && (k < EPS);
        int2 e;
        if (have) e = edges2[e0 + k];
        dst[ci] = v;
        if (have) {
            unsigned i = (unsigned)(e0 + k);
            upd2(mn1, mn2, e.x - lo, i);                       // forward half-edge
            upd2(mn1, mn2, e.y - lo, i + (unsigned)N_EDGES);   // reverse half-edge
        }
    }
    __syncthreads();

    for (int j = t; j < NPB; j += NTHR) {
        int n = lo + j;
        if (n < N_PTS)
            W[(size_t)ep * N_PTS + n] =
                ((unsigned long long)mn2[j] << 32) | (unsigned long long)mn1[j];
    }
}

__device__ __forceinline__ int quant6(float d) {
    // match jnp: clip(round((d + 1)/2 * 63), 0, 63); jnp.round = half-to-even -> rintf
    float x = ((d + 1.0f) / 2.0f) * 63.0f;
    float r = rintf(x);
    r = fminf(fmaxf(r, 0.0f), 63.0f);
    return (int)r;
}

__global__ void finalize(const float* __restrict__ pts, const float* __restrict__ tex,
                         const int2* __restrict__ edges,
                         const unsigned long long* __restrict__ W,
                         float* __restrict__ out) {
    int n = blockIdx.x * blockDim.x + threadIdx.x;
    if (n >= N_PTS) return;

    // merge EP per-slice (m1,m2) pairs -> global two smallest (all indices distinct)
    unsigned int k1 = 0xFFFFFFFFu, k2 = 0xFFFFFFFFu;
    #pragma unroll
    for (int s = 0; s < EP; ++s) {
        unsigned long long pr = W[(size_t)s * N_PTS + n];
        unsigned int m1 = (unsigned int)(pr & 0xFFFFFFFFu);
        unsigned int m2 = (unsigned int)(pr >> 32);
        if (m1 < k1) { k2 = k1; k1 = m1; } else if (m1 < k2) { k2 = m1; }
        if (m2 < k2 && m2 > k1) { k2 = m2; }
    }

    float px = pts[2 * n], py = pts[2 * n + 1];
    int t = (tex[n] > 0.7f) ? 1 : 0;

    int v0x = 0, v0y = 0, t0 = 0, v1x = 0, v1y = 0, t1 = 0;

    if (k1 < 2u * N_EDGES) {
        int k = (int)k1;
        int2 e = edges[(k < N_EDGES) ? k : (k - N_EDGES)];
        int dst = (k < N_EDGES) ? e.y : e.x;
        v0x = quant6(pts[2 * dst] - px);
        v0y = quant6(pts[2 * dst + 1] - py);
        t0 = (tex[dst] > 0.7f) ? 1 : 0;
    }
    if (k2 < 2u * N_EDGES) {
        int k = (int)k2;
        int2 e = edges[(k < N_EDGES) ? k : (k - N_EDGES)];
        int dst = (k < N_EDGES) ? e.y : e.x;
        v1x = quant6(pts[2 * dst] - px);
        v1y = quant6(pts[2 * dst + 1] - py);
        t1 = (tex[dst] > 0.7f) ? 1 : 0;
    }

    // hash keeps only cols 0..4 (col4 masked to 3 bits); each rel-variant
    // appears 6 times in rel_all (2 builds x 3 identity-rolls / 3 swap-rolls).
    int h_id = t | (v0x << 6) | (v0y << 12) | (t0 << 18) | ((v1x & 7) << 24);
    int h_sw = t | (v1x << 6) | (v1y << 12) | (t1 << 18) | ((v0x & 7) << 24);

    atomicAdd(&out[h_id], 6.0f);
    atomicAdd(&out[h_sw], 6.0f);
}

extern "C" void kernel_launch(void* const* d_in, const int* in_sizes, int n_in,
                              void* d_out, int out_size, void* d_ws, size_t ws_size,
                              hipStream_t stream) {
    const float* pts   = (const float*)d_in[0];
    const float* tex   = (const float*)d_in[1];
    const int2*  edges = (const int2*)d_in[2];   // int64 in ref -> int32 on device
    const float* mem   = (const float*)d_in[3];
    float*       out   = (float*)d_out;

    unsigned long long* W = (unsigned long long*)d_ws;   // 16 * 200K * 8B = 25.6 MB

    fused_copy_scan<<<NBLK, NTHR, 0, stream>>>(
        (const float4*)mem, (float4*)out, edges, W);
    finalize<<<(N_PTS + 255) / 256, 256, 0, stream>>>(pts, tex, edges, W, out);
}